// Round 13
// baseline (16209.540 us; speedup 1.0000x reference)
//
#include <hip/hip_runtime.h>
#include <hip/hip_cooperative_groups.h>
#include <math.h>

namespace cg = cooperative_groups;

#define T_ALL 200

typedef __attribute__((ext_vector_type(8)))  short v8s;
typedef __attribute__((ext_vector_type(16))) float v16f;

__device__ __forceinline__ unsigned short f2bf(float f) {
    unsigned int u = __float_as_uint(f);
    u += 0x7FFF + ((u >> 16) & 1);          // round-to-nearest-even
    return (unsigned short)(u >> 16);
}
__device__ __forceinline__ float bf2f(unsigned short s) {
    return __uint_as_float(((unsigned int)s) << 16);
}
__device__ __forceinline__ float sigf(float x) { return 1.0f / (1.0f + expf(-x)); }

// ---- ws layout (bytes) ----
#define A_FRAGS   6656ULL
#define A_HI_OFF  0ULL
#define A_LO_OFF  (A_FRAGS * 1024ULL)                    //  6,815,744
#define X_HI_OFF  (2ULL * A_FRAGS * 1024ULL)             // 13,631,488
#define X_BYTES   (200ULL * 256 * 128 * 2)               // 13,107,200
#define X_LO_OFF  (X_HI_OFF + X_BYTES)
#define H_BYTES   (2ULL * 256 * 512 * 2)                 // 524,288 per plane
#define HHI0_OFF  (X_LO_OFF + X_BYTES)
#define HLO0_OFF  (HHI0_OFF + H_BYTES)
#define HHI1_OFF  (HLO0_OFF + H_BYTES)
#define HLO1_OFF  (HHI1_OFF + H_BYTES)
#define B0PK_OFF  (HLO1_OFF + H_BYTES)
#define B1PK_OFF  (B0PK_OFF + 8192ULL)

// Pack W rows into MFMA 32x32x16 A-fragment order, bf16 hi/lo planes.
__global__ __launch_bounds__(64) void pack_w(
    const float* __restrict__ Wih0, const float* __restrict__ Whh0,
    const float* __restrict__ Wih1, const float* __restrict__ Whh1,
    unsigned short* __restrict__ Ahi, unsigned short* __restrict__ Alo)
{
    const int fi = blockIdx.x, lane = threadIdx.x;
    const float* W; int K, hg, c;
    if (fi < 512)       { W = Wih0; K = 128; hg = fi >> 3;          c = fi & 7;          }
    else if (fi < 2560) { W = Whh0; K = 512; hg = (fi - 512) >> 5;  c = (fi - 512) & 31; }
    else if (fi < 4608) { W = Wih1; K = 512; hg = (fi - 2560) >> 5; c = (fi - 2560) & 31;}
    else                { W = Whh1; K = 512; hg = (fi - 4608) >> 5; c = (fi - 4608) & 31;}
    const int m = lane & 31, half = lane >> 5;
    const int q = m & 3, hl = m >> 2;
    const int r = q * 512 + hg * 8 + hl;
    const int k0 = c * 16 + half * 8;
    const float* src = W + (size_t)r * K + k0;
    unsigned short* dh = Ahi + (size_t)fi * 512 + lane * 8;
    unsigned short* dl = Alo + (size_t)fi * 512 + lane * 8;
    #pragma unroll
    for (int j = 0; j < 8; ++j) {
        const float w = src[j];
        const unsigned short h = f2bf(w);
        dh[j] = h;
        dl[j] = f2bf(w - bf2f(h));
    }
}

// proposals [b][t][c] fp32 -> xHi/xLo [t][b][c] bf16
__global__ __launch_bounds__(256) void prep_x(const float* __restrict__ prop,
                                              unsigned short* __restrict__ xHi,
                                              unsigned short* __restrict__ xLo)
{
    const int t = blockIdx.x, b = threadIdx.x;
    const float* src = prop + ((size_t)b * 200 + t) * 128;
    unsigned short* dh = xHi + ((size_t)t * 256 + b) * 128;
    unsigned short* dl = xLo + ((size_t)t * 256 + b) * 128;
    #pragma unroll 4
    for (int c = 0; c < 128; ++c) {
        const float f = src[c];
        const unsigned short h = f2bf(f);
        dh[c] = h;
        dl[c] = f2bf(f - bf2f(h));
    }
}

// bias packs: bpk[hid] = float4 over gates (i,f,g,o)
__global__ __launch_bounds__(512) void pack_bias(
    const float* __restrict__ bih0, const float* __restrict__ bhh0,
    const float* __restrict__ bih1, const float* __restrict__ bhh1,
    float4* __restrict__ b0, float4* __restrict__ b1)
{
    const int hid = threadIdx.x;
    float4 u, v;
    u.x = bih0[hid] + bhh0[hid];
    u.y = bih0[512 + hid] + bhh0[512 + hid];
    u.z = bih0[1024 + hid] + bhh0[1024 + hid];
    u.w = bih0[1536 + hid] + bhh0[1536 + hid];
    v.x = bih1[hid] + bhh1[hid];
    v.y = bih1[512 + hid] + bhh1[512 + hid];
    v.z = bih1[1024 + hid] + bhh1[1024 + hid];
    v.w = bih1[1536 + hid] + bhh1[1536 + hid];
    b0[hid] = u; b1[hid] = v;
}

// COOPERATIVE persistent fused scan: all 201 supersteps in one launch;
// cg::grid().sync() per superstep does the correct release/acquire
// (waitcnt + L2 writeback/invalidate) so ALL memory ops are plain cached
// loads/stores — no atomics, no sc1, no spin protocol. 512 blocks x 256
// threads (2 blocks/CU co-resident). Wave = matvec mv: 0=Wih0*x[t],
// 1=Whh0*h0[t-1], 2=Wih1*h0[t-1], 3=Whh1*h1[t-2]; mv0/mv2 C-tiles pass via
// LDS to mv1/mv3 which do the in-thread LSTM update; c-state in registers.
__global__ __launch_bounds__(256, 2) void lstm_scan(
    const unsigned short* __restrict__ Ahi, const unsigned short* __restrict__ Alo,
    const unsigned short* __restrict__ xHi, const unsigned short* __restrict__ xLo,
    unsigned short* __restrict__ hHi0, unsigned short* __restrict__ hLo0,
    unsigned short* __restrict__ hHi1, unsigned short* __restrict__ hLo1,
    const float4* __restrict__ b0pk, const float4* __restrict__ b1pk)
{
    cg::grid_group grid = cg::this_grid();
    __shared__ float xch[2][32][32];                          // 8 KB C-tile exchange
    __shared__ __align__(16) unsigned short hst[2][2][32][8]; // 2 KB h staging
    const int tid  = threadIdx.x;
    const int mv   = tid >> 6, lane = tid & 63;
    const int f    = blockIdx.x;                  // 0..511
    const int hg   = (f & 7) * 8 + ((f >> 3) & 7);// 8 hgs per XCD (%8 round-robin)
    const int bgt  = f >> 6;                      // 0..7 batch tile (32 batches)
    const int ml   = lane & 31, half = lane >> 5;
    const int b    = bgt * 32 + ml;

    int fbase, nch;
    if (mv == 0)      { fbase = hg * 8;         nch = 8;  }
    else if (mv == 1) { fbase = 512 + hg * 32;  nch = 32; }
    else if (mv == 2) { fbase = 2560 + hg * 32; nch = 32; }
    else              { fbase = 4608 + hg * 32; nch = 32; }

    float4 bs[4];
    #pragma unroll
    for (int rq = 0; rq < 4; ++rq) {
        const int hid = hg * 8 + 2 * rq + half;
        bs[rq] = (mv == 1) ? b0pk[hid] : (mv == 3) ? b1pk[hid]
                                       : make_float4(0.f, 0.f, 0.f, 0.f);
    }
    float creg[4] = {0.f, 0.f, 0.f, 0.f};        // c-state lives in registers

    for (int t = 0; t <= T_ALL; ++t) {
        bool act;
        const unsigned short *bh_p, *bl_p;
        if (mv == 0) {
            act = (t < T_ALL);
            const size_t o = ((size_t)(act ? t : 0) * 256 + b) * 128;
            bh_p = xHi + o; bl_p = xLo + o;
        } else if (mv == 1) {
            act = (t >= 1 && t < T_ALL);
            const size_t o = ((size_t)((t + 1) & 1) * 256 + b) * 512;
            bh_p = hHi0 + o; bl_p = hLo0 + o;
        } else if (mv == 2) {
            act = (t >= 1);
            const size_t o = ((size_t)((t + 1) & 1) * 256 + b) * 512;
            bh_p = hHi0 + o; bl_p = hLo0 + o;
        } else {
            act = (t >= 2);
            const size_t o = ((size_t)(t & 1) * 256 + b) * 512;  // (t-2)&1 == t&1
            bh_p = hHi1 + o; bl_p = hLo1 + o;
        }

        v16f A0, A1;
        #pragma unroll
        for (int i = 0; i < 16; ++i) { A0[i] = 0.f; A1[i] = 0.f; }

        if (act) {
            #pragma unroll 8
            for (int c = 0; c < nch; ++c) {
                const v8s ah = *(const v8s*)(Ahi + ((size_t)(fbase + c)) * 512 + lane * 8);
                const v8s al = *(const v8s*)(Alo + ((size_t)(fbase + c)) * 512 + lane * 8);
                const v8s bh = *(const v8s*)(bh_p + c * 16 + half * 8);
                const v8s bl = *(const v8s*)(bl_p + c * 16 + half * 8);
                A0 = __builtin_amdgcn_mfma_f32_32x32x16_bf16(ah, bh, A0, 0, 0, 0);
                A1 = __builtin_amdgcn_mfma_f32_32x32x16_bf16(al, bh, A1, 0, 0, 0);
                A0 = __builtin_amdgcn_mfma_f32_32x32x16_bf16(ah, bl, A0, 0, 0, 0);
                A1 = __builtin_amdgcn_mfma_f32_32x32x16_bf16(al, bl, A1, 0, 0, 0);
            }
        }
        float av[16];
        #pragma unroll
        for (int i = 0; i < 16; ++i) av[i] = A0[i] + A1[i];

        if (mv == 0 || mv == 2) {
            const int s = mv >> 1;
            #pragma unroll
            for (int r = 0; r < 16; ++r)
                xch[s][(r & 3) + 8 * (r >> 2) + 4 * half][ml] = av[r];
        }
        __syncthreads();

        if (mv == 1 && t < T_ALL) {           // layer-0 update: h0[t]
            #pragma unroll
            for (int rq = 0; rq < 4; ++rq) {
                const int hl = 2 * rq + half;
                float a[4];
                #pragma unroll
                for (int j = 0; j < 4; ++j)
                    a[j] = av[rq * 4 + j] + xch[0][j + 8 * rq + 4 * half][ml]
                         + ((const float*)&bs[rq])[j];
                const float ig = sigf(a[0]), fg = sigf(a[1]);
                const float gg = tanhf(a[2]), og = sigf(a[3]);
                creg[rq] = fg * creg[rq] + ig * gg;
                const float h = og * tanhf(creg[rq]);
                const unsigned short hh = f2bf(h);
                hst[0][0][ml][hl] = hh;
                hst[0][1][ml][hl] = f2bf(h - bf2f(hh));
            }
        }
        if (mv == 3 && t >= 1) {              // layer-1 update: h1[t-1]
            #pragma unroll
            for (int rq = 0; rq < 4; ++rq) {
                const int hl = 2 * rq + half;
                float a[4];
                #pragma unroll
                for (int j = 0; j < 4; ++j)
                    a[j] = av[rq * 4 + j] + xch[1][j + 8 * rq + 4 * half][ml]
                         + ((const float*)&bs[rq])[j];
                const float ig = sigf(a[0]), fg = sigf(a[1]);
                const float gg = tanhf(a[2]), og = sigf(a[3]);
                creg[rq] = fg * creg[rq] + ig * gg;
                const float h = og * tanhf(creg[rq]);
                const unsigned short hh = f2bf(h);
                hst[1][0][ml][hl] = hh;
                hst[1][1][ml][hl] = f2bf(h - bf2f(hh));
            }
        }
        __syncthreads();

        // cooperative plain store of this block's h slice (8B per thread)
        {
            const int layer = tid >> 7, plane = (tid >> 6) & 1;
            const int bl_ = (tid >> 1) & 31, hq = tid & 1;
            const bool doit = (layer == 0) ? (t < T_ALL) : (t >= 1);
            if (doit) {
                const unsigned long long val =
                    *(const unsigned long long*)&hst[layer][plane][bl_][hq * 4];
                unsigned short* basep = (layer == 0) ? (plane ? hLo0 : hHi0)
                                                     : (plane ? hLo1 : hHi1);
                const int slot = (layer == 0) ? (t & 1) : ((t + 1) & 1);
                *(unsigned long long*)
                    (basep + ((size_t)slot * 256 + bgt * 32 + bl_) * 512 + hg * 8 + hq * 4)
                    = val;
            }
        }

        if (t < T_ALL) grid.sync();   // release + barrier + acquire (runtime-correct)
    }
}

// heads: base_feat = h1[:,199] (slot 1, hi+lo reconstruct) -> cls/bbox + 2 zeros
__global__ __launch_bounds__(64) void heads(
    const unsigned short* __restrict__ hHi1, const unsigned short* __restrict__ hLo1,
    const float4* __restrict__ clsW, const float* __restrict__ clsb,
    const float4* __restrict__ bbW, const float* __restrict__ bbb,
    float* __restrict__ out)
{
    const int b = blockIdx.x, j = threadIdx.x;
    const size_t off = (size_t)(256 + b) * 512;   // slot 1
    if (j < 42) {
        const float4* w = (j < 40) ? (clsW + (size_t)j * 128) : (bbW + (size_t)(j - 40) * 128);
        float acc = 0.f;
        #pragma unroll 4
        for (int k4 = 0; k4 < 128; ++k4) {
            const ushort4 hh = *(const ushort4*)(hHi1 + off + k4 * 4);
            const ushort4 hl = *(const ushort4*)(hLo1 + off + k4 * 4);
            const float4 wv = w[k4];
            acc += (bf2f(hh.x) + bf2f(hl.x)) * wv.x
                 + (bf2f(hh.y) + bf2f(hl.y)) * wv.y
                 + (bf2f(hh.z) + bf2f(hl.z)) * wv.z
                 + (bf2f(hh.w) + bf2f(hl.w)) * wv.w;
        }
        if (j < 40) out[(size_t)b * 40 + j] = acc + clsb[j];
        else        out[10240 + (size_t)b * 2 + (j - 40)] = acc + bbb[j - 40];
    }
    if (b == 0 && (j == 62 || j == 63)) out[10752 + (j - 62)] = 0.f;
}

extern "C" void kernel_launch(void* const* d_in, const int* in_sizes, int n_in,
                              void* d_out, int out_size, void* d_ws, size_t ws_size,
                              hipStream_t stream) {
    const float* proposals = (const float*)d_in[2];
    const float* Wih0 = (const float*)d_in[4];
    const float* Whh0 = (const float*)d_in[5];
    const float* bih0 = (const float*)d_in[6];
    const float* bhh0 = (const float*)d_in[7];
    const float* Wih1 = (const float*)d_in[8];
    const float* Whh1 = (const float*)d_in[9];
    const float* bih1 = (const float*)d_in[10];
    const float* bhh1 = (const float*)d_in[11];
    const float* clsW = (const float*)d_in[12];
    const float* clsb = (const float*)d_in[13];
    const float* bbW  = (const float*)d_in[14];
    const float* bbb  = (const float*)d_in[15];

    char* ws = (char*)d_ws;
    unsigned short* Ahi  = (unsigned short*)(ws + A_HI_OFF);
    unsigned short* Alo  = (unsigned short*)(ws + A_LO_OFF);
    unsigned short* xHi  = (unsigned short*)(ws + X_HI_OFF);
    unsigned short* xLo  = (unsigned short*)(ws + X_LO_OFF);
    unsigned short* hHi0 = (unsigned short*)(ws + HHI0_OFF);
    unsigned short* hLo0 = (unsigned short*)(ws + HLO0_OFF);
    unsigned short* hHi1 = (unsigned short*)(ws + HHI1_OFF);
    unsigned short* hLo1 = (unsigned short*)(ws + HLO1_OFF);
    float4* b0pk = (float4*)(ws + B0PK_OFF);
    float4* b1pk = (float4*)(ws + B1PK_OFF);

    pack_w<<<(int)A_FRAGS, 64, 0, stream>>>(Wih0, Whh0, Wih1, Whh1, Ahi, Alo);
    prep_x<<<200, 256, 0, stream>>>(proposals, xHi, xLo);
    pack_bias<<<1, 512, 0, stream>>>(bih0, bhh0, bih1, bhh1, b0pk, b1pk);

    void* args[] = {&Ahi, &Alo, &xHi, &xLo, &hHi0, &hLo0, &hHi1, &hLo1, &b0pk, &b1pk};
    hipLaunchCooperativeKernel((const void*)lstm_scan, dim3(512), dim3(256),
                               args, 0, stream);

    heads<<<256, 64, 0, stream>>>(hHi1, hLo1, (const float4*)clsW, clsb,
                                  (const float4*)bbW, bbb, (float*)d_out);
}

// Round 14
// 4297.108 us; speedup vs baseline: 3.7722x; 3.7722x over previous
//
#include <hip/hip_runtime.h>
#include <math.h>

#define T_ALL 200
#define ROWB  1040   // 1024 B h-row + 16 B pad (16B-aligned, spreads LDS banks)

typedef __attribute__((ext_vector_type(8)))  short v8s;
typedef __attribute__((ext_vector_type(16))) float v16f;

typedef __attribute__((address_space(1))) const unsigned int g_u32;
typedef __attribute__((address_space(3))) unsigned int l_u32;

// device-coherent global->LDS: aux=16 (sc1) reads the L3 coherence point,
// bypassing the possibly-stale local L2. Proven correct for cross-XCD h in R4-R6.
__device__ __forceinline__ void gl2lds16_coh(const void* g, void* l) {
    __builtin_amdgcn_global_load_lds((g_u32*)g, (l_u32*)l, 16, 0, 16);
}

__device__ __forceinline__ unsigned short f2bf(float f) {
    unsigned int u = __float_as_uint(f);
    u += 0x7FFF + ((u >> 16) & 1);          // round-to-nearest-even
    return (unsigned short)(u >> 16);
}
__device__ __forceinline__ float bf2f(unsigned short s) {
    return __uint_as_float(((unsigned int)s) << 16);
}
__device__ __forceinline__ float sigf(float x) { return 1.0f / (1.0f + expf(-x)); }

// ---- ws layout (bytes) ----
#define A_FRAGS   6656ULL
#define A_HI_OFF  0ULL
#define A_LO_OFF  (A_FRAGS * 1024ULL)
#define X_HI_OFF  (2ULL * A_FRAGS * 1024ULL)
#define X_BYTES   (200ULL * 256 * 128 * 2)
#define X_LO_OFF  (X_HI_OFF + X_BYTES)
#define H_BYTES   (2ULL * 256 * 512 * 2)
#define HHI0_OFF  (X_LO_OFF + X_BYTES)
#define HLO0_OFF  (HHI0_OFF + H_BYTES)
#define HHI1_OFF  (HLO0_OFF + H_BYTES)
#define HLO1_OFF  (HHI1_OFF + H_BYTES)
#define B0PK_OFF  (HLO1_OFF + H_BYTES)
#define B1PK_OFF  (B0PK_OFF + 8192ULL)
#define ARR_OFF   (B1PK_OFF + 8192ULL)
#define ARR_BYTES (512ULL * 64)              // one 64B-spread arrive slot per block

// Pack W rows into MFMA 32x32x16 A-fragment order, bf16 hi/lo planes.
__global__ __launch_bounds__(64) void pack_w(
    const float* __restrict__ Wih0, const float* __restrict__ Whh0,
    const float* __restrict__ Wih1, const float* __restrict__ Whh1,
    unsigned short* __restrict__ Ahi, unsigned short* __restrict__ Alo)
{
    const int fi = blockIdx.x, lane = threadIdx.x;
    const float* W; int K, hg, c;
    if (fi < 512)       { W = Wih0; K = 128; hg = fi >> 3;          c = fi & 7;          }
    else if (fi < 2560) { W = Whh0; K = 512; hg = (fi - 512) >> 5;  c = (fi - 512) & 31; }
    else if (fi < 4608) { W = Wih1; K = 512; hg = (fi - 2560) >> 5; c = (fi - 2560) & 31;}
    else                { W = Whh1; K = 512; hg = (fi - 4608) >> 5; c = (fi - 4608) & 31;}
    const int m = lane & 31, half = lane >> 5;
    const int q = m & 3, hl = m >> 2;
    const int r = q * 512 + hg * 8 + hl;
    const int k0 = c * 16 + half * 8;
    const float* src = W + (size_t)r * K + k0;
    unsigned short* dh = Ahi + (size_t)fi * 512 + lane * 8;
    unsigned short* dl = Alo + (size_t)fi * 512 + lane * 8;
    #pragma unroll
    for (int j = 0; j < 8; ++j) {
        const float w = src[j];
        const unsigned short h = f2bf(w);
        dh[j] = h;
        dl[j] = f2bf(w - bf2f(h));
    }
}

// proposals [b][t][c] fp32 -> xHi/xLo [t][b][c] bf16
__global__ __launch_bounds__(256) void prep_x(const float* __restrict__ prop,
                                              unsigned short* __restrict__ xHi,
                                              unsigned short* __restrict__ xLo)
{
    const int t = blockIdx.x, b = threadIdx.x;
    const float* src = prop + ((size_t)b * 200 + t) * 128;
    unsigned short* dh = xHi + ((size_t)t * 256 + b) * 128;
    unsigned short* dl = xLo + ((size_t)t * 256 + b) * 128;
    #pragma unroll 4
    for (int c = 0; c < 128; ++c) {
        const float f = src[c];
        const unsigned short h = f2bf(f);
        dh[c] = h;
        dl[c] = f2bf(f - bf2f(h));
    }
}

// bias packs: bpk[hid] = float4 over gates (i,f,g,o)
__global__ __launch_bounds__(512) void pack_bias(
    const float* __restrict__ bih0, const float* __restrict__ bhh0,
    const float* __restrict__ bih1, const float* __restrict__ bhh1,
    float4* __restrict__ b0, float4* __restrict__ b1)
{
    const int hid = threadIdx.x;
    float4 u, v;
    u.x = bih0[hid] + bhh0[hid];
    u.y = bih0[512 + hid] + bhh0[512 + hid];
    u.z = bih0[1024 + hid] + bhh0[1024 + hid];
    u.w = bih0[1536 + hid] + bhh0[1536 + hid];
    v.x = bih1[hid] + bhh1[hid];
    v.y = bih1[512 + hid] + bhh1[512 + hid];
    v.z = bih1[1024 + hid] + bhh1[1024 + hid];
    v.w = bih1[1536 + hid] + bhh1[1536 + hid];
    b0[hid] = u; b1[hid] = v;
}

// PERSISTENT fused scan, both R12 stalls fixed:
//  - h staged via sc1 global_load_lds into a 2x32.5KB LDS double buffer
//    (pipelined, shared by mv1+mv2) — not per-lane atomic loads.
//  - barrier = distributed store-arrive array (no RMW serialization) +
//    all-wave 64-slot relaxed poll. Weights/x plain cached -> L2-hot all scan.
// 512 blocks x 256 threads (2/CU). Block = (hg, batch tile of 32); wave = mv:
// 0=Wih0*x[t], 1=Whh0*h0[t-1], 2=Wih1*h0[t-1], 3=Whh1*h1[t-2]. Per step,
// 4 staging rounds: h0hi, h0lo (consumed by mv1/mv2), h1hi, h1lo (mv3).
// c-state in registers. Epilogue h -> LDS -> cooperative 8B agent stores.
__global__ __launch_bounds__(256, 2) void lstm_scan(
    const unsigned short* __restrict__ Ahi, const unsigned short* __restrict__ Alo,
    const unsigned short* __restrict__ xHi, const unsigned short* __restrict__ xLo,
    unsigned short* __restrict__ hHi0, unsigned short* __restrict__ hLo0,
    unsigned short* __restrict__ hHi1, unsigned short* __restrict__ hLo1,
    const float4* __restrict__ b0pk, const float4* __restrict__ b1pk,
    int* __restrict__ arr)
{
    __shared__ __align__(16) unsigned char dbuf[2][32 * ROWB];   // 66,560 B
    __shared__ float xch[2][32][32];                             //  8,192 B
    __shared__ __align__(16) unsigned short hst[2][2][32][8];    //  2,048 B

    const int tid  = threadIdx.x;
    const int mv   = tid >> 6, lane = tid & 63;
    const int f    = blockIdx.x;                   // 0..511
    const int hg   = (f & 7) * 8 + ((f >> 3) & 7); // 8 hgs/XCD if %8 round-robin
    const int bt   = f >> 6;                       // batch tile 0..7 = sync group
    const int ml   = lane & 31, half = lane >> 5;

    int fbase;
    if (mv == 0)      fbase = hg * 8;
    else if (mv == 1) fbase = 512 + hg * 32;
    else if (mv == 2) fbase = 2560 + hg * 32;
    else              fbase = 4608 + hg * 32;

    float4 bs[4];
    #pragma unroll
    for (int rq = 0; rq < 4; ++rq) {
        const int hid = hg * 8 + 2 * rq + half;
        bs[rq] = (mv == 1) ? b0pk[hid] : (mv == 3) ? b1pk[hid]
                                       : make_float4(0.f, 0.f, 0.f, 0.f);
    }
    float creg[4] = {0.f, 0.f, 0.f, 0.f};

    for (int t = 0; t <= T_ALL; ++t) {
        const int rs0 = (t + 1) & 1;   // h0[t-1] slot
        const int rs1 = t & 1;         // h1[t-2] slot
        const unsigned short* src[4] = {
            hHi0 + ((size_t)rs0 * 256 + bt * 32) * 512,
            hLo0 + ((size_t)rs0 * 256 + bt * 32) * 512,
            hHi1 + ((size_t)rs1 * 256 + bt * 32) * 512,
            hLo1 + ((size_t)rs1 * 256 + bt * 32) * 512 };

        const bool a12 = (mv == 1) ? (t >= 1 && t < T_ALL)
                       : (mv == 2) ? (t >= 1) : false;
        const bool a3  = (mv == 3) && (t >= 2);

        v16f A0, A1;
        #pragma unroll
        for (int i = 0; i < 16; ++i) { A0[i] = 0.f; A1[i] = 0.f; }

        // stage round 0 (h0 hi) -> dbuf[0]
        #pragma unroll
        for (int j = 0; j < 8; ++j) {
            const int row = mv * 8 + j;
            gl2lds16_coh(src[0] + (size_t)row * 512 + lane * 8, &dbuf[0][row * ROWB]);
        }
        __syncthreads();

        // phase 0: stage r1 -> dbuf[1]; mv0 x-matvec; mv1/mv2 hi products
        #pragma unroll
        for (int j = 0; j < 8; ++j) {
            const int row = mv * 8 + j;
            gl2lds16_coh(src[1] + (size_t)row * 512 + lane * 8, &dbuf[1][row * ROWB]);
        }
        if (mv == 0 && t < T_ALL) {
            const unsigned short* xh = xHi + ((size_t)t * 256 + bt * 32 + ml) * 128 + half * 8;
            const unsigned short* xl = xLo + ((size_t)t * 256 + bt * 32 + ml) * 128 + half * 8;
            #pragma unroll
            for (int c = 0; c < 8; ++c) {
                const v8s ah = *(const v8s*)(Ahi + ((size_t)(fbase + c)) * 512 + lane * 8);
                const v8s al = *(const v8s*)(Alo + ((size_t)(fbase + c)) * 512 + lane * 8);
                const v8s bh = *(const v8s*)(xh + c * 16);
                const v8s bl = *(const v8s*)(xl + c * 16);
                A0 = __builtin_amdgcn_mfma_f32_32x32x16_bf16(ah, bh, A0, 0, 0, 0);
                A1 = __builtin_amdgcn_mfma_f32_32x32x16_bf16(al, bh, A1, 0, 0, 0);
                A0 = __builtin_amdgcn_mfma_f32_32x32x16_bf16(ah, bl, A0, 0, 0, 0);
                A1 = __builtin_amdgcn_mfma_f32_32x32x16_bf16(al, bl, A1, 0, 0, 0);
            }
            #pragma unroll
            for (int r = 0; r < 16; ++r)
                xch[0][(r & 3) + 8 * (r >> 2) + 4 * half][ml] = A0[r] + A1[r];
        }
        if (a12) {
            #pragma unroll 8
            for (int c = 0; c < 32; ++c) {
                const v8s ah = *(const v8s*)(Ahi + ((size_t)(fbase + c)) * 512 + lane * 8);
                const v8s al = *(const v8s*)(Alo + ((size_t)(fbase + c)) * 512 + lane * 8);
                const v8s bf = *(const v8s*)(&dbuf[0][ml * ROWB + c * 32 + half * 16]);
                A0 = __builtin_amdgcn_mfma_f32_32x32x16_bf16(ah, bf, A0, 0, 0, 0);
                A1 = __builtin_amdgcn_mfma_f32_32x32x16_bf16(al, bf, A1, 0, 0, 0);
            }
        }
        __syncthreads();

        // phase 1: stage r2 (h1 hi) -> dbuf[0]; mv1/mv2 lo products; mv2 -> xch[1]
        #pragma unroll
        for (int j = 0; j < 8; ++j) {
            const int row = mv * 8 + j;
            gl2lds16_coh(src[2] + (size_t)row * 512 + lane * 8, &dbuf[0][row * ROWB]);
        }
        if (a12) {
            #pragma unroll 8
            for (int c = 0; c < 32; ++c) {
                const v8s ah = *(const v8s*)(Ahi + ((size_t)(fbase + c)) * 512 + lane * 8);
                const v8s al = *(const v8s*)(Alo + ((size_t)(fbase + c)) * 512 + lane * 8);
                const v8s bf = *(const v8s*)(&dbuf[1][ml * ROWB + c * 32 + half * 16]);
                A0 = __builtin_amdgcn_mfma_f32_32x32x16_bf16(ah, bf, A0, 0, 0, 0);
                A1 = __builtin_amdgcn_mfma_f32_32x32x16_bf16(al, bf, A1, 0, 0, 0);
            }
            if (mv == 2) {
                #pragma unroll
                for (int r = 0; r < 16; ++r)
                    xch[1][(r & 3) + 8 * (r >> 2) + 4 * half][ml] = A0[r] + A1[r];
            }
        }
        __syncthreads();

        // phase 2: stage r3 (h1 lo) -> dbuf[1]; mv3 hi products
        #pragma unroll
        for (int j = 0; j < 8; ++j) {
            const int row = mv * 8 + j;
            gl2lds16_coh(src[3] + (size_t)row * 512 + lane * 8, &dbuf[1][row * ROWB]);
        }
        if (a3) {
            #pragma unroll 8
            for (int c = 0; c < 32; ++c) {
                const v8s ah = *(const v8s*)(Ahi + ((size_t)(fbase + c)) * 512 + lane * 8);
                const v8s al = *(const v8s*)(Alo + ((size_t)(fbase + c)) * 512 + lane * 8);
                const v8s bf = *(const v8s*)(&dbuf[0][ml * ROWB + c * 32 + half * 16]);
                A0 = __builtin_amdgcn_mfma_f32_32x32x16_bf16(ah, bf, A0, 0, 0, 0);
                A1 = __builtin_amdgcn_mfma_f32_32x32x16_bf16(al, bf, A1, 0, 0, 0);
            }
        }
        __syncthreads();

        // phase 3: mv3 lo products
        if (a3) {
            #pragma unroll 8
            for (int c = 0; c < 32; ++c) {
                const v8s ah = *(const v8s*)(Ahi + ((size_t)(fbase + c)) * 512 + lane * 8);
                const v8s al = *(const v8s*)(Alo + ((size_t)(fbase + c)) * 512 + lane * 8);
                const v8s bf = *(const v8s*)(&dbuf[1][ml * ROWB + c * 32 + half * 16]);
                A0 = __builtin_amdgcn_mfma_f32_32x32x16_bf16(ah, bf, A0, 0, 0, 0);
                A1 = __builtin_amdgcn_mfma_f32_32x32x16_bf16(al, bf, A1, 0, 0, 0);
            }
        }

        // epilogue: in-thread LSTM updates (C layout: 4 gates of a hid per thread)
        if (mv == 1 && t < T_ALL) {
            #pragma unroll
            for (int rq = 0; rq < 4; ++rq) {
                const int hl = 2 * rq + half;
                float a[4];
                #pragma unroll
                for (int j = 0; j < 4; ++j)
                    a[j] = A0[rq * 4 + j] + A1[rq * 4 + j]
                         + xch[0][j + 8 * rq + 4 * half][ml]
                         + ((const float*)&bs[rq])[j];
                const float ig = sigf(a[0]), fg = sigf(a[1]);
                const float gg = tanhf(a[2]), og = sigf(a[3]);
                creg[rq] = fg * creg[rq] + ig * gg;
                const float h = og * tanhf(creg[rq]);
                const unsigned short hh = f2bf(h);
                hst[0][0][ml][hl] = hh;
                hst[0][1][ml][hl] = f2bf(h - bf2f(hh));
            }
        }
        if (mv == 3 && t >= 1) {
            #pragma unroll
            for (int rq = 0; rq < 4; ++rq) {
                const int hl = 2 * rq + half;
                float a[4];
                #pragma unroll
                for (int j = 0; j < 4; ++j)
                    a[j] = A0[rq * 4 + j] + A1[rq * 4 + j]
                         + xch[1][j + 8 * rq + 4 * half][ml]
                         + ((const float*)&bs[rq])[j];
                const float ig = sigf(a[0]), fg = sigf(a[1]);
                const float gg = tanhf(a[2]), og = sigf(a[3]);
                creg[rq] = fg * creg[rq] + ig * gg;
                const float h = og * tanhf(creg[rq]);
                const unsigned short hh = f2bf(h);
                hst[1][0][ml][hl] = hh;
                hst[1][1][ml][hl] = f2bf(h - bf2f(hh));
            }
        }
        __syncthreads();

        // cooperative device-coherent h store (8B per thread)
        {
            const int layer = tid >> 7, plane = (tid >> 6) & 1;
            const int bl = (tid >> 1) & 31, hq = tid & 1;
            const bool doit = (layer == 0) ? (t < T_ALL) : (t >= 1);
            if (doit) {
                const unsigned long long val =
                    *(const unsigned long long*)&hst[layer][plane][bl][hq * 4];
                unsigned short* basep = (layer == 0) ? (plane ? hLo0 : hHi0)
                                                     : (plane ? hLo1 : hHi1);
                const int slot = (layer == 0) ? (t & 1) : ((t + 1) & 1);
                unsigned long long* dst = (unsigned long long*)
                    (basep + ((size_t)slot * 256 + bt * 32 + bl) * 512 + hg * 8 + hq * 4);
                __hip_atomic_store(dst, val, __ATOMIC_RELAXED, __HIP_MEMORY_SCOPE_AGENT);
            }
        }

        if (t < T_ALL) {
            __threadfence_block();       // drain h stores (vmcnt)
            __syncthreads();
            if (tid == 0)
                __hip_atomic_store(arr + (size_t)f * 16, t + 1,
                                   __ATOMIC_RELAXED, __HIP_MEMORY_SCOPE_AGENT);
            // all waves poll the 64 arrive slots of this batch-tile group
            int v;
            do {
                v = __hip_atomic_load(arr + ((size_t)bt * 64 + lane) * 16,
                                      __ATOMIC_RELAXED, __HIP_MEMORY_SCOPE_AGENT);
                if (__all(v >= t + 1)) break;
                __builtin_amdgcn_s_sleep(1);
            } while (true);
            __syncthreads();
        }
    }
}

// heads: base_feat = h1[:,199] (slot 1, hi+lo reconstruct) -> cls/bbox + 2 zeros
__global__ __launch_bounds__(64) void heads(
    const unsigned short* __restrict__ hHi1, const unsigned short* __restrict__ hLo1,
    const float4* __restrict__ clsW, const float* __restrict__ clsb,
    const float4* __restrict__ bbW, const float* __restrict__ bbb,
    float* __restrict__ out)
{
    const int b = blockIdx.x, j = threadIdx.x;
    const size_t off = (size_t)(256 + b) * 512;   // slot 1
    if (j < 42) {
        const float4* w = (j < 40) ? (clsW + (size_t)j * 128) : (bbW + (size_t)(j - 40) * 128);
        float acc = 0.f;
        #pragma unroll 4
        for (int k4 = 0; k4 < 128; ++k4) {
            const ushort4 hh = *(const ushort4*)(hHi1 + off + k4 * 4);
            const ushort4 hl = *(const ushort4*)(hLo1 + off + k4 * 4);
            const float4 wv = w[k4];
            acc += (bf2f(hh.x) + bf2f(hl.x)) * wv.x
                 + (bf2f(hh.y) + bf2f(hl.y)) * wv.y
                 + (bf2f(hh.z) + bf2f(hl.z)) * wv.z
                 + (bf2f(hh.w) + bf2f(hl.w)) * wv.w;
        }
        if (j < 40) out[(size_t)b * 40 + j] = acc + clsb[j];
        else        out[10240 + (size_t)b * 2 + (j - 40)] = acc + bbb[j - 40];
    }
    if (b == 0 && (j == 62 || j == 63)) out[10752 + (j - 62)] = 0.f;
}

extern "C" void kernel_launch(void* const* d_in, const int* in_sizes, int n_in,
                              void* d_out, int out_size, void* d_ws, size_t ws_size,
                              hipStream_t stream) {
    const float* proposals = (const float*)d_in[2];
    const float* Wih0 = (const float*)d_in[4];
    const float* Whh0 = (const float*)d_in[5];
    const float* bih0 = (const float*)d_in[6];
    const float* bhh0 = (const float*)d_in[7];
    const float* Wih1 = (const float*)d_in[8];
    const float* Whh1 = (const float*)d_in[9];
    const float* bih1 = (const float*)d_in[10];
    const float* bhh1 = (const float*)d_in[11];
    const float* clsW = (const float*)d_in[12];
    const float* clsb = (const float*)d_in[13];
    const float* bbW  = (const float*)d_in[14];
    const float* bbb  = (const float*)d_in[15];

    char* ws = (char*)d_ws;
    unsigned short* Ahi  = (unsigned short*)(ws + A_HI_OFF);
    unsigned short* Alo  = (unsigned short*)(ws + A_LO_OFF);
    unsigned short* xHi  = (unsigned short*)(ws + X_HI_OFF);
    unsigned short* xLo  = (unsigned short*)(ws + X_LO_OFF);
    unsigned short* hHi0 = (unsigned short*)(ws + HHI0_OFF);
    unsigned short* hLo0 = (unsigned short*)(ws + HLO0_OFF);
    unsigned short* hHi1 = (unsigned short*)(ws + HHI1_OFF);
    unsigned short* hLo1 = (unsigned short*)(ws + HLO1_OFF);
    float4* b0pk = (float4*)(ws + B0PK_OFF);
    float4* b1pk = (float4*)(ws + B1PK_OFF);
    int*    arr  = (int*)(ws + ARR_OFF);

    hipMemsetAsync(arr, 0, ARR_BYTES, stream);

    pack_w<<<(int)A_FRAGS, 64, 0, stream>>>(Wih0, Whh0, Wih1, Whh1, Ahi, Alo);
    prep_x<<<200, 256, 0, stream>>>(proposals, xHi, xLo);
    pack_bias<<<1, 512, 0, stream>>>(bih0, bhh0, bih1, bhh1, b0pk, b1pk);

    lstm_scan<<<512, 256, 0, stream>>>(Ahi, Alo, xHi, xLo,
                                       hHi0, hLo0, hHi1, hLo1,
                                       b0pk, b1pk, arr);

    heads<<<256, 64, 0, stream>>>(hHi1, hLo1, (const float4*)clsW, clsb,
                                  (const float4*)bbW, bbb, (float*)d_out);
}

// Round 15
// 2759.467 us; speedup vs baseline: 5.8742x; 1.5572x over previous
//
#include <hip/hip_runtime.h>
#include <math.h>

#define T_ALL 200
#define ROWB  1040                 // 1024 B h-row + 16 B pad (16B-aligned)
#define QUAD  (32 * ROWB)          // 33,280 B per h quadrant

typedef __attribute__((ext_vector_type(8)))  short v8s;
typedef __attribute__((ext_vector_type(16))) float v16f;

typedef __attribute__((address_space(1))) const unsigned int g_u32;
typedef __attribute__((address_space(3))) unsigned int l_u32;

// device-coherent global->LDS: aux=16 (sc1) reads the L3 coherence point,
// bypassing the possibly-stale local L2 (proven R4-R6, R14).
__device__ __forceinline__ void gl2lds16_coh(const void* g, void* l) {
    __builtin_amdgcn_global_load_lds((g_u32*)g, (l_u32*)l, 16, 0, 16);
}

__device__ __forceinline__ unsigned short f2bf(float f) {
    unsigned int u = __float_as_uint(f);
    u += 0x7FFF + ((u >> 16) & 1);          // round-to-nearest-even
    return (unsigned short)(u >> 16);
}
__device__ __forceinline__ float bf2f(unsigned short s) {
    return __uint_as_float(((unsigned int)s) << 16);
}
__device__ __forceinline__ float sigf(float x) { return 1.0f / (1.0f + expf(-x)); }

// ---- ws layout (bytes) ----
#define A_FRAGS   6656ULL
#define A_HI_OFF  0ULL
#define A_LO_OFF  (A_FRAGS * 1024ULL)
#define X_HI_OFF  (2ULL * A_FRAGS * 1024ULL)
#define X_BYTES   (200ULL * 256 * 128 * 2)
#define X_LO_OFF  (X_HI_OFF + X_BYTES)
#define H_BYTES   (2ULL * 256 * 512 * 2)
#define HHI0_OFF  (X_LO_OFF + X_BYTES)
#define HLO0_OFF  (HHI0_OFF + H_BYTES)
#define HHI1_OFF  (HLO0_OFF + H_BYTES)
#define HLO1_OFF  (HHI1_OFF + H_BYTES)
#define B0PK_OFF  (HLO1_OFF + H_BYTES)
#define B1PK_OFF  (B0PK_OFF + 8192ULL)
#define ARR_OFF   (B1PK_OFF + 8192ULL)
#define ARR_BYTES (256ULL * 64)              // one 64B-spread arrive slot per block

// Pack W rows into MFMA 32x32x16 A-fragment order, bf16 hi/lo planes.
__global__ __launch_bounds__(64) void pack_w(
    const float* __restrict__ Wih0, const float* __restrict__ Whh0,
    const float* __restrict__ Wih1, const float* __restrict__ Whh1,
    unsigned short* __restrict__ Ahi, unsigned short* __restrict__ Alo)
{
    const int fi = blockIdx.x, lane = threadIdx.x;
    const float* W; int K, hg, c;
    if (fi < 512)       { W = Wih0; K = 128; hg = fi >> 3;          c = fi & 7;          }
    else if (fi < 2560) { W = Whh0; K = 512; hg = (fi - 512) >> 5;  c = (fi - 512) & 31; }
    else if (fi < 4608) { W = Wih1; K = 512; hg = (fi - 2560) >> 5; c = (fi - 2560) & 31;}
    else                { W = Whh1; K = 512; hg = (fi - 4608) >> 5; c = (fi - 4608) & 31;}
    const int m = lane & 31, half = lane >> 5;
    const int q = m & 3, hl = m >> 2;
    const int r = q * 512 + hg * 8 + hl;
    const int k0 = c * 16 + half * 8;
    const float* src = W + (size_t)r * K + k0;
    unsigned short* dh = Ahi + (size_t)fi * 512 + lane * 8;
    unsigned short* dl = Alo + (size_t)fi * 512 + lane * 8;
    #pragma unroll
    for (int j = 0; j < 8; ++j) {
        const float w = src[j];
        const unsigned short h = f2bf(w);
        dh[j] = h;
        dl[j] = f2bf(w - bf2f(h));
    }
}

// proposals [b][t][c] fp32 -> xHi/xLo [t][b][c] bf16
__global__ __launch_bounds__(256) void prep_x(const float* __restrict__ prop,
                                              unsigned short* __restrict__ xHi,
                                              unsigned short* __restrict__ xLo)
{
    const int t = blockIdx.x, b = threadIdx.x;
    const float* src = prop + ((size_t)b * 200 + t) * 128;
    unsigned short* dh = xHi + ((size_t)t * 256 + b) * 128;
    unsigned short* dl = xLo + ((size_t)t * 256 + b) * 128;
    #pragma unroll 4
    for (int c = 0; c < 128; ++c) {
        const float f = src[c];
        const unsigned short h = f2bf(f);
        dh[c] = h;
        dl[c] = f2bf(f - bf2f(h));
    }
}

// bias packs: bpk[hid] = float4 over gates (i,f,g,o)
__global__ __launch_bounds__(512) void pack_bias(
    const float* __restrict__ bih0, const float* __restrict__ bhh0,
    const float* __restrict__ bih1, const float* __restrict__ bhh1,
    float4* __restrict__ b0, float4* __restrict__ b1)
{
    const int hid = threadIdx.x;
    float4 u, v;
    u.x = bih0[hid] + bhh0[hid];
    u.y = bih0[512 + hid] + bhh0[512 + hid];
    u.z = bih0[1024 + hid] + bhh0[1024 + hid];
    u.w = bih0[1536 + hid] + bhh0[1536 + hid];
    v.x = bih1[hid] + bhh1[hid];
    v.y = bih1[512 + hid] + bhh1[512 + hid];
    v.z = bih1[1024 + hid] + bhh1[1024 + hid];
    v.w = bih1[1536 + hid] + bhh1[1536 + hid];
    b0[hid] = u; b1[hid] = v;
}

// PERSISTENT fused scan, single-burst staging: 256 blocks x 512 threads
// (1 block/CU, all 256 co-resident; 8 waves = 2/SIMD). Block = (hg-pair,
// 32-batch tile). All four h quadrants (h0hi,h0lo,h1hi,h1lo = 130 KB w/ pad)
// stage in ONE gl2lds burst -> ONE latency-exposed drain per step (R14 had 4).
// Wave w: mv = w>>1 (0=Wih0*x, 1=Whh0*h0, 2=Wih1*h0, 3=Whh1*h1), hgi = w&1.
// Weights/x plain cached (L2-resident whole scan). Barrier: distributed
// store-arrive (32 slots/group) + all-wave poll. c-state in registers.
__global__ __launch_bounds__(512) void lstm_scan(
    const unsigned short* __restrict__ Ahi, const unsigned short* __restrict__ Alo,
    const unsigned short* __restrict__ xHi, const unsigned short* __restrict__ xLo,
    unsigned short* __restrict__ hHi0, unsigned short* __restrict__ hLo0,
    unsigned short* __restrict__ hHi1, unsigned short* __restrict__ hLo1,
    const float4* __restrict__ b0pk, const float4* __restrict__ b1pk,
    int* __restrict__ arr)
{
    __shared__ __align__(16) unsigned char dbuf[4 * QUAD];       // 133,120 B
    __shared__ float xch[2][2][32][32];                          //  16,384 B
    __shared__ __align__(16) unsigned short hst[2][2][32][16];   //   4,096 B

    const int tid  = threadIdx.x;
    const int wv   = tid >> 6, lane = tid & 63;
    const int mv   = wv >> 1, hgi = wv & 1;
    const int f    = blockIdx.x;                   // 0..255
    const int hgp  = (f & 7) * 4 + ((f >> 3) & 3); // 4 hg-pairs per XCD
    const int bt   = f >> 5;                       // batch tile 0..7 = sync group
    const int hg   = hgp * 2 + hgi;                // hid group 0..63
    const int ml   = lane & 31, half = lane >> 5;

    int fbase;
    if (mv == 0)      fbase = hg * 8;
    else if (mv == 1) fbase = 512 + hg * 32;
    else if (mv == 2) fbase = 2560 + hg * 32;
    else              fbase = 4608 + hg * 32;

    float4 bs[4];
    #pragma unroll
    for (int rq = 0; rq < 4; ++rq) {
        const int hid = hg * 8 + 2 * rq + half;
        bs[rq] = (mv == 1) ? b0pk[hid] : (mv == 3) ? b1pk[hid]
                                       : make_float4(0.f, 0.f, 0.f, 0.f);
    }
    float creg[4] = {0.f, 0.f, 0.f, 0.f};

    for (int t = 0; t <= T_ALL; ++t) {
        const int rs0 = (t + 1) & 1;   // h0[t-1] slot
        const int rs1 = t & 1;         // h1[t-2] slot
        const unsigned short* srcq[4] = {
            hHi0 + ((size_t)rs0 * 256 + bt * 32) * 512,
            hLo0 + ((size_t)rs0 * 256 + bt * 32) * 512,
            hHi1 + ((size_t)rs1 * 256 + bt * 32) * 512,
            hLo1 + ((size_t)rs1 * 256 + bt * 32) * 512 };

        // ---- single staging burst: 128 rows (4 quadrants x 32 batches) ----
        #pragma unroll
        for (int j = 0; j < 16; ++j) {
            const int row = wv * 16 + j;
            const int q = row >> 5, r = row & 31;
            gl2lds16_coh(srcq[q] + (size_t)r * 512 + lane * 8,
                         &dbuf[q * QUAD + r * ROWB]);
        }

        v16f A0, A1;
        #pragma unroll
        for (int i = 0; i < 16; ++i) { A0[i] = 0.f; A1[i] = 0.f; }

        // mv0: x-matvec (plain loads, independent of dbuf) before the drain
        if (mv == 0 && t < T_ALL) {
            const unsigned short* xh = xHi + ((size_t)t * 256 + bt * 32 + ml) * 128 + half * 8;
            const unsigned short* xl = xLo + ((size_t)t * 256 + bt * 32 + ml) * 128 + half * 8;
            #pragma unroll
            for (int c = 0; c < 8; ++c) {
                const v8s ah = *(const v8s*)(Ahi + ((size_t)(fbase + c)) * 512 + lane * 8);
                const v8s al = *(const v8s*)(Alo + ((size_t)(fbase + c)) * 512 + lane * 8);
                const v8s bh = *(const v8s*)(xh + c * 16);
                const v8s bl = *(const v8s*)(xl + c * 16);
                A0 = __builtin_amdgcn_mfma_f32_32x32x16_bf16(ah, bh, A0, 0, 0, 0);
                A1 = __builtin_amdgcn_mfma_f32_32x32x16_bf16(al, bh, A1, 0, 0, 0);
                A0 = __builtin_amdgcn_mfma_f32_32x32x16_bf16(ah, bl, A0, 0, 0, 0);
                A1 = __builtin_amdgcn_mfma_f32_32x32x16_bf16(al, bl, A1, 0, 0, 0);
            }
            #pragma unroll
            for (int r = 0; r < 16; ++r)
                xch[0][hgi][(r & 3) + 8 * (r >> 2) + 4 * half][ml] = A0[r] + A1[r];
            #pragma unroll
            for (int i = 0; i < 16; ++i) { A0[i] = 0.f; A1[i] = 0.f; }
        }
        __syncthreads();   // staging drained + xch[0] published

        // ---- recurrent matvecs from LDS (h0 for mv1/mv2, h1 for mv3) ----
        const bool a12 = (mv == 1) ? (t >= 1 && t < T_ALL)
                       : (mv == 2) ? (t >= 1) : false;
        const bool a3  = (mv == 3) && (t >= 2);
        if (a12 || a3) {
            const unsigned char* qhi = dbuf + (mv == 3 ? 2 : 0) * QUAD;
            const unsigned char* qlo = qhi + QUAD;
            #pragma unroll 8
            for (int c = 0; c < 32; ++c) {
                const v8s ah = *(const v8s*)(Ahi + ((size_t)(fbase + c)) * 512 + lane * 8);
                const v8s al = *(const v8s*)(Alo + ((size_t)(fbase + c)) * 512 + lane * 8);
                const v8s bh = *(const v8s*)(qhi + ml * ROWB + c * 32 + half * 16);
                const v8s bl = *(const v8s*)(qlo + ml * ROWB + c * 32 + half * 16);
                A0 = __builtin_amdgcn_mfma_f32_32x32x16_bf16(ah, bh, A0, 0, 0, 0);
                A1 = __builtin_amdgcn_mfma_f32_32x32x16_bf16(al, bh, A1, 0, 0, 0);
                A0 = __builtin_amdgcn_mfma_f32_32x32x16_bf16(ah, bl, A0, 0, 0, 0);
                A1 = __builtin_amdgcn_mfma_f32_32x32x16_bf16(al, bl, A1, 0, 0, 0);
            }
        }

        // mv1: full epilogue now (xch[0] already published)
        if (mv == 1 && t < T_ALL) {
            #pragma unroll
            for (int rq = 0; rq < 4; ++rq) {
                const int hl = 2 * rq + half;
                float a[4];
                #pragma unroll
                for (int j = 0; j < 4; ++j)
                    a[j] = A0[rq * 4 + j] + A1[rq * 4 + j]
                         + xch[0][hgi][j + 8 * rq + 4 * half][ml]
                         + ((const float*)&bs[rq])[j];
                const float ig = sigf(a[0]), fg = sigf(a[1]);
                const float gg = tanhf(a[2]), og = sigf(a[3]);
                creg[rq] = fg * creg[rq] + ig * gg;
                const float h = og * tanhf(creg[rq]);
                const unsigned short hh = f2bf(h);
                hst[0][0][ml][hgi * 8 + hl] = hh;
                hst[0][1][ml][hgi * 8 + hl] = f2bf(h - bf2f(hh));
            }
        }
        if (mv == 2 && t >= 1) {
            #pragma unroll
            for (int r = 0; r < 16; ++r)
                xch[1][hgi][(r & 3) + 8 * (r >> 2) + 4 * half][ml] = A0[r] + A1[r];
        }
        __syncthreads();   // xch[1] + hst[0] published

        // mv3 epilogue: layer-1 update h1[t-1]
        if (mv == 3 && t >= 1) {
            #pragma unroll
            for (int rq = 0; rq < 4; ++rq) {
                const int hl = 2 * rq + half;
                float a[4];
                #pragma unroll
                for (int j = 0; j < 4; ++j)
                    a[j] = A0[rq * 4 + j] + A1[rq * 4 + j]
                         + xch[1][hgi][j + 8 * rq + 4 * half][ml]
                         + ((const float*)&bs[rq])[j];
                const float ig = sigf(a[0]), fg = sigf(a[1]);
                const float gg = tanhf(a[2]), og = sigf(a[3]);
                creg[rq] = fg * creg[rq] + ig * gg;
                const float h = og * tanhf(creg[rq]);
                const unsigned short hh = f2bf(h);
                hst[1][0][ml][hgi * 8 + hl] = hh;
                hst[1][1][ml][hgi * 8 + hl] = f2bf(h - bf2f(hh));
            }
        }
        __syncthreads();   // hst[1] published

        // cooperative device-coherent h store (8B per thread, 4 KB total)
        {
            const int layer = tid >> 8, plane = (tid >> 7) & 1;
            const int bl = (tid >> 2) & 31, hq = tid & 3;
            const bool doit = (layer == 0) ? (t < T_ALL) : (t >= 1);
            if (doit) {
                const unsigned long long val =
                    *(const unsigned long long*)&hst[layer][plane][bl][hq * 4];
                unsigned short* basep = (layer == 0) ? (plane ? hLo0 : hHi0)
                                                     : (plane ? hLo1 : hHi1);
                const int slot = (layer == 0) ? (t & 1) : ((t + 1) & 1);
                unsigned long long* dst = (unsigned long long*)
                    (basep + ((size_t)slot * 256 + bt * 32 + bl) * 512 + hgp * 16 + hq * 4);
                __hip_atomic_store(dst, val, __ATOMIC_RELAXED, __HIP_MEMORY_SCOPE_AGENT);
            }
        }

        if (t < T_ALL) {
            __threadfence_block();       // drain h stores (vmcnt)
            __syncthreads();
            if (tid == 0)
                __hip_atomic_store(arr + (size_t)f * 16, t + 1,
                                   __ATOMIC_RELAXED, __HIP_MEMORY_SCOPE_AGENT);
            // all waves poll the 32 arrive slots of this batch-tile group
            int v = 0x7FFFFFFF;
            do {
                if (lane < 32)
                    v = __hip_atomic_load(arr + ((size_t)bt * 32 + lane) * 16,
                                          __ATOMIC_RELAXED, __HIP_MEMORY_SCOPE_AGENT);
                if (__all(lane >= 32 || v >= t + 1)) break;
                __builtin_amdgcn_s_sleep(1);
            } while (true);
            __syncthreads();
        }
    }
}

// heads: base_feat = h1[:,199] (slot 1, hi+lo reconstruct) -> cls/bbox + 2 zeros
__global__ __launch_bounds__(64) void heads(
    const unsigned short* __restrict__ hHi1, const unsigned short* __restrict__ hLo1,
    const float4* __restrict__ clsW, const float* __restrict__ clsb,
    const float4* __restrict__ bbW, const float* __restrict__ bbb,
    float* __restrict__ out)
{
    const int b = blockIdx.x, j = threadIdx.x;
    const size_t off = (size_t)(256 + b) * 512;   // slot 1
    if (j < 42) {
        const float4* w = (j < 40) ? (clsW + (size_t)j * 128) : (bbW + (size_t)(j - 40) * 128);
        float acc = 0.f;
        #pragma unroll 4
        for (int k4 = 0; k4 < 128; ++k4) {
            const ushort4 hh = *(const ushort4*)(hHi1 + off + k4 * 4);
            const ushort4 hl = *(const ushort4*)(hLo1 + off + k4 * 4);
            const float4 wv = w[k4];
            acc += (bf2f(hh.x) + bf2f(hl.x)) * wv.x
                 + (bf2f(hh.y) + bf2f(hl.y)) * wv.y
                 + (bf2f(hh.z) + bf2f(hl.z)) * wv.z
                 + (bf2f(hh.w) + bf2f(hl.w)) * wv.w;
        }
        if (j < 40) out[(size_t)b * 40 + j] = acc + clsb[j];
        else        out[10240 + (size_t)b * 2 + (j - 40)] = acc + bbb[j - 40];
    }
    if (b == 0 && (j == 62 || j == 63)) out[10752 + (j - 62)] = 0.f;
}

extern "C" void kernel_launch(void* const* d_in, const int* in_sizes, int n_in,
                              void* d_out, int out_size, void* d_ws, size_t ws_size,
                              hipStream_t stream) {
    const float* proposals = (const float*)d_in[2];
    const float* Wih0 = (const float*)d_in[4];
    const float* Whh0 = (const float*)d_in[5];
    const float* bih0 = (const float*)d_in[6];
    const float* bhh0 = (const float*)d_in[7];
    const float* Wih1 = (const float*)d_in[8];
    const float* Whh1 = (const float*)d_in[9];
    const float* bih1 = (const float*)d_in[10];
    const float* bhh1 = (const float*)d_in[11];
    const float* clsW = (const float*)d_in[12];
    const float* clsb = (const float*)d_in[13];
    const float* bbW  = (const float*)d_in[14];
    const float* bbb  = (const float*)d_in[15];

    char* ws = (char*)d_ws;
    unsigned short* Ahi  = (unsigned short*)(ws + A_HI_OFF);
    unsigned short* Alo  = (unsigned short*)(ws + A_LO_OFF);
    unsigned short* xHi  = (unsigned short*)(ws + X_HI_OFF);
    unsigned short* xLo  = (unsigned short*)(ws + X_LO_OFF);
    unsigned short* hHi0 = (unsigned short*)(ws + HHI0_OFF);
    unsigned short* hLo0 = (unsigned short*)(ws + HLO0_OFF);
    unsigned short* hHi1 = (unsigned short*)(ws + HHI1_OFF);
    unsigned short* hLo1 = (unsigned short*)(ws + HLO1_OFF);
    float4* b0pk = (float4*)(ws + B0PK_OFF);
    float4* b1pk = (float4*)(ws + B1PK_OFF);
    int*    arr  = (int*)(ws + ARR_OFF);

    hipMemsetAsync(arr, 0, ARR_BYTES, stream);

    pack_w<<<(int)A_FRAGS, 64, 0, stream>>>(Wih0, Whh0, Wih1, Whh1, Ahi, Alo);
    prep_x<<<200, 256, 0, stream>>>(proposals, xHi, xLo);
    pack_bias<<<1, 512, 0, stream>>>(bih0, bhh0, bih1, bhh1, b0pk, b1pk);

    lstm_scan<<<256, 512, 0, stream>>>(Ahi, Alo, xHi, xLo,
                                       hHi0, hLo0, hHi1, hLo1,
                                       b0pk, b1pk, arr);

    heads<<<256, 64, 0, stream>>>(hHi1, hLo1, (const float4*)clsW, clsb,
                                  (const float4*)bbW, bbb, (float*)d_out);
}

// Round 16
// 2438.098 us; speedup vs baseline: 6.6484x; 1.1318x over previous
//
#include <hip/hip_runtime.h>
#include <math.h>

#define T_ALL 200
#define ROWB  1040                 // 1024 B h-row + 16 B pad (16B-aligned)
#define QUAD  (32 * ROWB)          // 33,280 B per h quadrant

typedef __attribute__((ext_vector_type(8)))  short v8s;
typedef __attribute__((ext_vector_type(16))) float v16f;

typedef __attribute__((address_space(1))) const unsigned int g_u32;
typedef __attribute__((address_space(3))) unsigned int l_u32;

// device-coherent global->LDS: aux=16 (sc1) reads the L3 coherence point,
// bypassing the possibly-stale local L2 (proven R4-R6, R14, R15).
__device__ __forceinline__ void gl2lds16_coh(const void* g, void* l) {
    __builtin_amdgcn_global_load_lds((g_u32*)g, (l_u32*)l, 16, 0, 16);
}

__device__ __forceinline__ unsigned short f2bf(float f) {
    unsigned int u = __float_as_uint(f);
    u += 0x7FFF + ((u >> 16) & 1);          // round-to-nearest-even
    return (unsigned short)(u >> 16);
}
__device__ __forceinline__ float bf2f(unsigned short s) {
    return __uint_as_float(((unsigned int)s) << 16);
}
// hardware-exp transcendentals (v_exp_f32): ~1e-7 error, saturation-safe
__device__ __forceinline__ float sigf(float x)  { return 1.0f / (1.0f + __expf(-x)); }
__device__ __forceinline__ float tanhf_hw(float x) {
    return 1.0f - 2.0f / (__expf(2.0f * x) + 1.0f);   // e=inf -> 1; e=0 -> -1
}

// ---- ws layout (bytes) ----
#define A_FRAGS   6656ULL
#define A_HI_OFF  0ULL
#define A_LO_OFF  (A_FRAGS * 1024ULL)
#define X_HI_OFF  (2ULL * A_FRAGS * 1024ULL)
#define X_BYTES   (200ULL * 256 * 128 * 2)
#define X_LO_OFF  (X_HI_OFF + X_BYTES)
#define H_BYTES   (2ULL * 256 * 512 * 2)
#define HHI0_OFF  (X_LO_OFF + X_BYTES)
#define HLO0_OFF  (HHI0_OFF + H_BYTES)
#define HHI1_OFF  (HLO0_OFF + H_BYTES)
#define HLO1_OFF  (HHI1_OFF + H_BYTES)
#define B0PK_OFF  (HLO1_OFF + H_BYTES)
#define B1PK_OFF  (B0PK_OFF + 8192ULL)
#define ARR_OFF   (B1PK_OFF + 8192ULL)
#define ARR_BYTES (256ULL * 64)              // one 64B-spread arrive slot per block

// Pack W rows into MFMA 32x32x16 A-fragment order, bf16 hi/lo planes.
__global__ __launch_bounds__(64) void pack_w(
    const float* __restrict__ Wih0, const float* __restrict__ Whh0,
    const float* __restrict__ Wih1, const float* __restrict__ Whh1,
    unsigned short* __restrict__ Ahi, unsigned short* __restrict__ Alo)
{
    const int fi = blockIdx.x, lane = threadIdx.x;
    const float* W; int K, hg, c;
    if (fi < 512)       { W = Wih0; K = 128; hg = fi >> 3;          c = fi & 7;          }
    else if (fi < 2560) { W = Whh0; K = 512; hg = (fi - 512) >> 5;  c = (fi - 512) & 31; }
    else if (fi < 4608) { W = Wih1; K = 512; hg = (fi - 2560) >> 5; c = (fi - 2560) & 31;}
    else                { W = Whh1; K = 512; hg = (fi - 4608) >> 5; c = (fi - 4608) & 31;}
    const int m = lane & 31, half = lane >> 5;
    const int q = m & 3, hl = m >> 2;
    const int r = q * 512 + hg * 8 + hl;
    const int k0 = c * 16 + half * 8;
    const float* src = W + (size_t)r * K + k0;
    unsigned short* dh = Ahi + (size_t)fi * 512 + lane * 8;
    unsigned short* dl = Alo + (size_t)fi * 512 + lane * 8;
    #pragma unroll
    for (int j = 0; j < 8; ++j) {
        const float w = src[j];
        const unsigned short h = f2bf(w);
        dh[j] = h;
        dl[j] = f2bf(w - bf2f(h));
    }
}

// proposals [b][t][c] fp32 -> xHi/xLo [t][b][c] bf16
__global__ __launch_bounds__(256) void prep_x(const float* __restrict__ prop,
                                              unsigned short* __restrict__ xHi,
                                              unsigned short* __restrict__ xLo)
{
    const int t = blockIdx.x, b = threadIdx.x;
    const float* src = prop + ((size_t)b * 200 + t) * 128;
    unsigned short* dh = xHi + ((size_t)t * 256 + b) * 128;
    unsigned short* dl = xLo + ((size_t)t * 256 + b) * 128;
    #pragma unroll 4
    for (int c = 0; c < 128; ++c) {
        const float f = src[c];
        const unsigned short h = f2bf(f);
        dh[c] = h;
        dl[c] = f2bf(f - bf2f(h));
    }
}

// bias packs: bpk[hid] = float4 over gates (i,f,g,o)
__global__ __launch_bounds__(512) void pack_bias(
    const float* __restrict__ bih0, const float* __restrict__ bhh0,
    const float* __restrict__ bih1, const float* __restrict__ bhh1,
    float4* __restrict__ b0, float4* __restrict__ b1)
{
    const int hid = threadIdx.x;
    float4 u, v;
    u.x = bih0[hid] + bhh0[hid];
    u.y = bih0[512 + hid] + bhh0[512 + hid];
    u.z = bih0[1024 + hid] + bhh0[1024 + hid];
    u.w = bih0[1536 + hid] + bhh0[1536 + hid];
    v.x = bih1[hid] + bhh1[hid];
    v.y = bih1[512 + hid] + bhh1[512 + hid];
    v.z = bih1[1024 + hid] + bhh1[1024 + hid];
    v.w = bih1[1536 + hid] + bhh1[1536 + hid];
    b0[hid] = u; b1[hid] = v;
}

// PERSISTENT fused scan (R15 structure) with 3-product split-bf16
// (a*b ~= ah*bh + al*bh + ah*bl; dropped al*bl term ~2^-16 relative) and
// hardware-exp gate activations. 256 blocks x 512 threads (1 block/CU).
// Block = (hg-pair, 32-batch tile); wave w: mv = w>>1 (0=Wih0*x, 1=Whh0*h0,
// 2=Wih1*h0, 3=Whh1*h1), hgi = w&1. Single gl2lds staging burst per step;
// weights/x plain cached (L2-resident); distributed store-arrive barrier.
__global__ __launch_bounds__(512) void lstm_scan(
    const unsigned short* __restrict__ Ahi, const unsigned short* __restrict__ Alo,
    const unsigned short* __restrict__ xHi, const unsigned short* __restrict__ xLo,
    unsigned short* __restrict__ hHi0, unsigned short* __restrict__ hLo0,
    unsigned short* __restrict__ hHi1, unsigned short* __restrict__ hLo1,
    const float4* __restrict__ b0pk, const float4* __restrict__ b1pk,
    int* __restrict__ arr)
{
    __shared__ __align__(16) unsigned char dbuf[4 * QUAD];       // 133,120 B
    __shared__ float xch[2][2][32][32];                          //  16,384 B
    __shared__ __align__(16) unsigned short hst[2][2][32][16];   //   4,096 B

    const int tid  = threadIdx.x;
    const int wv   = tid >> 6, lane = tid & 63;
    const int mv   = wv >> 1, hgi = wv & 1;
    const int f    = blockIdx.x;                   // 0..255
    const int hgp  = (f & 7) * 4 + ((f >> 3) & 3); // 4 hg-pairs per XCD
    const int bt   = f >> 5;                       // batch tile 0..7 = sync group
    const int hg   = hgp * 2 + hgi;                // hid group 0..63
    const int ml   = lane & 31, half = lane >> 5;

    int fbase;
    if (mv == 0)      fbase = hg * 8;
    else if (mv == 1) fbase = 512 + hg * 32;
    else if (mv == 2) fbase = 2560 + hg * 32;
    else              fbase = 4608 + hg * 32;

    float4 bs[4];
    #pragma unroll
    for (int rq = 0; rq < 4; ++rq) {
        const int hid = hg * 8 + 2 * rq + half;
        bs[rq] = (mv == 1) ? b0pk[hid] : (mv == 3) ? b1pk[hid]
                                       : make_float4(0.f, 0.f, 0.f, 0.f);
    }
    float creg[4] = {0.f, 0.f, 0.f, 0.f};

    for (int t = 0; t <= T_ALL; ++t) {
        const int rs0 = (t + 1) & 1;   // h0[t-1] slot
        const int rs1 = t & 1;         // h1[t-2] slot
        const unsigned short* srcq[4] = {
            hHi0 + ((size_t)rs0 * 256 + bt * 32) * 512,
            hLo0 + ((size_t)rs0 * 256 + bt * 32) * 512,
            hHi1 + ((size_t)rs1 * 256 + bt * 32) * 512,
            hLo1 + ((size_t)rs1 * 256 + bt * 32) * 512 };

        // ---- single staging burst: 128 rows (4 quadrants x 32 batches) ----
        #pragma unroll
        for (int j = 0; j < 16; ++j) {
            const int row = wv * 16 + j;
            const int q = row >> 5, r = row & 31;
            gl2lds16_coh(srcq[q] + (size_t)r * 512 + lane * 8,
                         &dbuf[q * QUAD + r * ROWB]);
        }

        v16f A0, A1;
        #pragma unroll
        for (int i = 0; i < 16; ++i) { A0[i] = 0.f; A1[i] = 0.f; }

        // mv0: x-matvec (plain loads, independent of dbuf) before the drain
        if (mv == 0 && t < T_ALL) {
            const unsigned short* xh = xHi + ((size_t)t * 256 + bt * 32 + ml) * 128 + half * 8;
            const unsigned short* xl = xLo + ((size_t)t * 256 + bt * 32 + ml) * 128 + half * 8;
            #pragma unroll
            for (int c = 0; c < 8; ++c) {
                const v8s ah = *(const v8s*)(Ahi + ((size_t)(fbase + c)) * 512 + lane * 8);
                const v8s al = *(const v8s*)(Alo + ((size_t)(fbase + c)) * 512 + lane * 8);
                const v8s bh = *(const v8s*)(xh + c * 16);
                const v8s bl = *(const v8s*)(xl + c * 16);
                A0 = __builtin_amdgcn_mfma_f32_32x32x16_bf16(ah, bh, A0, 0, 0, 0);
                A1 = __builtin_amdgcn_mfma_f32_32x32x16_bf16(al, bh, A1, 0, 0, 0);
                A1 = __builtin_amdgcn_mfma_f32_32x32x16_bf16(ah, bl, A1, 0, 0, 0);
            }
            #pragma unroll
            for (int r = 0; r < 16; ++r)
                xch[0][hgi][(r & 3) + 8 * (r >> 2) + 4 * half][ml] = A0[r] + A1[r];
            #pragma unroll
            for (int i = 0; i < 16; ++i) { A0[i] = 0.f; A1[i] = 0.f; }
        }
        __syncthreads();   // staging drained + xch[0] published

        // ---- recurrent matvecs from LDS (h0 for mv1/mv2, h1 for mv3) ----
        const bool a12 = (mv == 1) ? (t >= 1 && t < T_ALL)
                       : (mv == 2) ? (t >= 1) : false;
        const bool a3  = (mv == 3) && (t >= 2);
        if (a12 || a3) {
            const unsigned char* qhi = dbuf + (mv == 3 ? 2 : 0) * QUAD;
            const unsigned char* qlo = qhi + QUAD;
            #pragma unroll 8
            for (int c = 0; c < 32; ++c) {
                const v8s ah = *(const v8s*)(Ahi + ((size_t)(fbase + c)) * 512 + lane * 8);
                const v8s al = *(const v8s*)(Alo + ((size_t)(fbase + c)) * 512 + lane * 8);
                const v8s bh = *(const v8s*)(qhi + ml * ROWB + c * 32 + half * 16);
                const v8s bl = *(const v8s*)(qlo + ml * ROWB + c * 32 + half * 16);
                A0 = __builtin_amdgcn_mfma_f32_32x32x16_bf16(ah, bh, A0, 0, 0, 0);
                A1 = __builtin_amdgcn_mfma_f32_32x32x16_bf16(al, bh, A1, 0, 0, 0);
                A1 = __builtin_amdgcn_mfma_f32_32x32x16_bf16(ah, bl, A1, 0, 0, 0);
            }
        }

        // mv1: full epilogue now (xch[0] already published)
        if (mv == 1 && t < T_ALL) {
            #pragma unroll
            for (int rq = 0; rq < 4; ++rq) {
                const int hl = 2 * rq + half;
                float a[4];
                #pragma unroll
                for (int j = 0; j < 4; ++j)
                    a[j] = A0[rq * 4 + j] + A1[rq * 4 + j]
                         + xch[0][hgi][j + 8 * rq + 4 * half][ml]
                         + ((const float*)&bs[rq])[j];
                const float ig = sigf(a[0]), fg = sigf(a[1]);
                const float gg = tanhf_hw(a[2]), og = sigf(a[3]);
                creg[rq] = fg * creg[rq] + ig * gg;
                const float h = og * tanhf_hw(creg[rq]);
                const unsigned short hh = f2bf(h);
                hst[0][0][ml][hgi * 8 + hl] = hh;
                hst[0][1][ml][hgi * 8 + hl] = f2bf(h - bf2f(hh));
            }
        }
        if (mv == 2 && t >= 1) {
            #pragma unroll
            for (int r = 0; r < 16; ++r)
                xch[1][hgi][(r & 3) + 8 * (r >> 2) + 4 * half][ml] = A0[r] + A1[r];
        }
        __syncthreads();   // xch[1] + hst[0] published

        // mv3 epilogue: layer-1 update h1[t-1]
        if (mv == 3 && t >= 1) {
            #pragma unroll
            for (int rq = 0; rq < 4; ++rq) {
                const int hl = 2 * rq + half;
                float a[4];
                #pragma unroll
                for (int j = 0; j < 4; ++j)
                    a[j] = A0[rq * 4 + j] + A1[rq * 4 + j]
                         + xch[1][hgi][j + 8 * rq + 4 * half][ml]
                         + ((const float*)&bs[rq])[j];
                const float ig = sigf(a[0]), fg = sigf(a[1]);
                const float gg = tanhf_hw(a[2]), og = sigf(a[3]);
                creg[rq] = fg * creg[rq] + ig * gg;
                const float h = og * tanhf_hw(creg[rq]);
                const unsigned short hh = f2bf(h);
                hst[1][0][ml][hgi * 8 + hl] = hh;
                hst[1][1][ml][hgi * 8 + hl] = f2bf(h - bf2f(hh));
            }
        }
        __syncthreads();   // hst[1] published

        // cooperative device-coherent h store (8B per thread, 4 KB total)
        {
            const int layer = tid >> 8, plane = (tid >> 7) & 1;
            const int bl = (tid >> 2) & 31, hq = tid & 3;
            const bool doit = (layer == 0) ? (t < T_ALL) : (t >= 1);
            if (doit) {
                const unsigned long long val =
                    *(const unsigned long long*)&hst[layer][plane][bl][hq * 4];
                unsigned short* basep = (layer == 0) ? (plane ? hLo0 : hHi0)
                                                     : (plane ? hLo1 : hHi1);
                const int slot = (layer == 0) ? (t & 1) : ((t + 1) & 1);
                unsigned long long* dst = (unsigned long long*)
                    (basep + ((size_t)slot * 256 + bt * 32 + bl) * 512 + hgp * 16 + hq * 4);
                __hip_atomic_store(dst, val, __ATOMIC_RELAXED, __HIP_MEMORY_SCOPE_AGENT);
            }
        }

        if (t < T_ALL) {
            __threadfence_block();       // drain h stores (vmcnt)
            __syncthreads();
            if (tid == 0)
                __hip_atomic_store(arr + (size_t)f * 16, t + 1,
                                   __ATOMIC_RELAXED, __HIP_MEMORY_SCOPE_AGENT);
            // all waves poll the 32 arrive slots of this batch-tile group
            int v = 0x7FFFFFFF;
            do {
                if (lane < 32)
                    v = __hip_atomic_load(arr + ((size_t)bt * 32 + lane) * 16,
                                          __ATOMIC_RELAXED, __HIP_MEMORY_SCOPE_AGENT);
                if (__all(lane >= 32 || v >= t + 1)) break;
                __builtin_amdgcn_s_sleep(1);
            } while (true);
            __syncthreads();
        }
    }
}

// heads: base_feat = h1[:,199] (slot 1, hi+lo reconstruct) -> cls/bbox + 2 zeros
__global__ __launch_bounds__(64) void heads(
    const unsigned short* __restrict__ hHi1, const unsigned short* __restrict__ hLo1,
    const float4* __restrict__ clsW, const float* __restrict__ clsb,
    const float4* __restrict__ bbW, const float* __restrict__ bbb,
    float* __restrict__ out)
{
    const int b = blockIdx.x, j = threadIdx.x;
    const size_t off = (size_t)(256 + b) * 512;   // slot 1
    if (j < 42) {
        const float4* w = (j < 40) ? (clsW + (size_t)j * 128) : (bbW + (size_t)(j - 40) * 128);
        float acc = 0.f;
        #pragma unroll 4
        for (int k4 = 0; k4 < 128; ++k4) {
            const ushort4 hh = *(const ushort4*)(hHi1 + off + k4 * 4);
            const ushort4 hl = *(const ushort4*)(hLo1 + off + k4 * 4);
            const float4 wv = w[k4];
            acc += (bf2f(hh.x) + bf2f(hl.x)) * wv.x
                 + (bf2f(hh.y) + bf2f(hl.y)) * wv.y
                 + (bf2f(hh.z) + bf2f(hl.z)) * wv.z
                 + (bf2f(hh.w) + bf2f(hl.w)) * wv.w;
        }
        if (j < 40) out[(size_t)b * 40 + j] = acc + clsb[j];
        else        out[10240 + (size_t)b * 2 + (j - 40)] = acc + bbb[j - 40];
    }
    if (b == 0 && (j == 62 || j == 63)) out[10752 + (j - 62)] = 0.f;
}

extern "C" void kernel_launch(void* const* d_in, const int* in_sizes, int n_in,
                              void* d_out, int out_size, void* d_ws, size_t ws_size,
                              hipStream_t stream) {
    const float* proposals = (const float*)d_in[2];
    const float* Wih0 = (const float*)d_in[4];
    const float* Whh0 = (const float*)d_in[5];
    const float* bih0 = (const float*)d_in[6];
    const float* bhh0 = (const float*)d_in[7];
    const float* Wih1 = (const float*)d_in[8];
    const float* Whh1 = (const float*)d_in[9];
    const float* bih1 = (const float*)d_in[10];
    const float* bhh1 = (const float*)d_in[11];
    const float* clsW = (const float*)d_in[12];
    const float* clsb = (const float*)d_in[13];
    const float* bbW  = (const float*)d_in[14];
    const float* bbb  = (const float*)d_in[15];

    char* ws = (char*)d_ws;
    unsigned short* Ahi  = (unsigned short*)(ws + A_HI_OFF);
    unsigned short* Alo  = (unsigned short*)(ws + A_LO_OFF);
    unsigned short* xHi  = (unsigned short*)(ws + X_HI_OFF);
    unsigned short* xLo  = (unsigned short*)(ws + X_LO_OFF);
    unsigned short* hHi0 = (unsigned short*)(ws + HHI0_OFF);
    unsigned short* hLo0 = (unsigned short*)(ws + HLO0_OFF);
    unsigned short* hHi1 = (unsigned short*)(ws + HHI1_OFF);
    unsigned short* hLo1 = (unsigned short*)(ws + HLO1_OFF);
    float4* b0pk = (float4*)(ws + B0PK_OFF);
    float4* b1pk = (float4*)(ws + B1PK_OFF);
    int*    arr  = (int*)(ws + ARR_OFF);

    hipMemsetAsync(arr, 0, ARR_BYTES, stream);

    pack_w<<<(int)A_FRAGS, 64, 0, stream>>>(Wih0, Whh0, Wih1, Whh1, Ahi, Alo);
    prep_x<<<200, 256, 0, stream>>>(proposals, xHi, xLo);
    pack_bias<<<1, 512, 0, stream>>>(bih0, bhh0, bih1, bhh1, b0pk, b1pk);

    lstm_scan<<<256, 512, 0, stream>>>(Ahi, Alo, xHi, xLo,
                                       hHi0, hLo0, hHi1, hLo1,
                                       b0pk, b1pk, arr);

    heads<<<256, 64, 0, stream>>>(hHi1, hLo1, (const float4*)clsW, clsb,
                                  (const float4*)bbW, bbb, (float*)d_out);
}